// Round 8
// baseline (351.651 us; speedup 1.0000x reference)
//
#include <hip/hip_runtime.h>
#include <cstdint>

typedef float f32x4 __attribute__((ext_vector_type(4)));
typedef __bf16 bf16x8 __attribute__((ext_vector_type(8)));
typedef __bf16 bf16x4 __attribute__((ext_vector_type(4)));

// Problem constants
// B=2, D=256, L=512, NL=2, DS=16, DC=4
// group a: tokens M=512,  dm=512, di=1024, r=32, NX->64, P=8,  KS=8
// group b: tokens M=1024, dm=256, di=512,  r=16, NX->64, P=16, KS=4
#define SCAN_TC 32

// ---------------- weight f32 -> bf16 conversion (4 big segments) ----------------
__global__ __launch_bounds__(256)
void cvt4(const float* __restrict__ s0, const float* __restrict__ s1,
          const float* __restrict__ s2, const float* __restrict__ s3,
          __bf16* __restrict__ d0, __bf16* __restrict__ d1,
          __bf16* __restrict__ d2, __bf16* __restrict__ d3,
          int n0, int n1, int n2, int n3)
{
    int idx = (blockIdx.x * 256 + threadIdx.x) * 4;
    const float* s; __bf16* d; int off;
    if (idx < n0) { s = s0; d = d0; off = idx; }
    else if (idx < n0 + n1) { s = s1; d = d1; off = idx - n0; }
    else if (idx < n0 + n1 + n2) { s = s2; d = d2; off = idx - n0 - n1; }
    else if (idx < n0 + n1 + n2 + n3) { s = s3; d = d3; off = idx - n0 - n1 - n2; }
    else return;
    f32x4 v = *(const f32x4*)(s + off);
    bf16x4 o;
#pragma unroll
    for (int j = 0; j < 4; ++j) o[j] = (__bf16)v[j];
    *(bf16x4*)(d + off) = o;
}

// ------- padded conversion: xproj rows pad to 64 (group b 48->64) -------
__device__ __forceinline__ void cvt_pad_one(const float* src, __bf16* dst, int rem,
                                            int rs, int cs, int rd, int cd)
{
    const int c = rem % cd;
    const int rfull = rem / cd;
    const int layer = rfull / rd;
    const int r = rfull % rd;
    float v = (r < rs && c < cs) ? src[((size_t)layer * rs + r) * cs + c] : 0.f;
    dst[rem] = (__bf16)v;
}

__global__ __launch_bounds__(256)
void cvt_pad2(const float* __restrict__ xp_a, const float* __restrict__ xp_b,
              __bf16* __restrict__ o_xp_a, __bf16* __restrict__ o_xp_b)
{
    const int n0 = 131072, n1 = 65536;
    int idx = blockIdx.x * 256 + threadIdx.x;
    if (idx < n0) cvt_pad_one(xp_a, o_xp_a, idx, 64, 1024, 64, 1024);
    else if (idx < n0 + n1) cvt_pad_one(xp_b, o_xp_b, idx - n0, 48, 512, 64, 512);
}

// ---------------- MFMA GEMM: C(M,N) = A(M,K) @ W(N,K)^T ----------------
__global__ __launch_bounds__(256)
void gemm_bf16(const float* __restrict__ A, const __bf16* __restrict__ W,
               float* __restrict__ C, int M, int N, int K)
{
    __shared__ __bf16 sA[64 * 64];
    __shared__ __bf16 sW[64 * 64];
    const int tid = threadIdx.x;
    const int bm = blockIdx.y * 64, bn = blockIdx.x * 64;
    const int lane = tid & 63, wv = tid >> 6;
    const int m_off = (wv & 1) * 32, n_off = (wv >> 1) * 32;
    const int fr = lane & 15, fq = lane >> 4;
    f32x4 acc[2][2] = {};

    for (int k0 = 0; k0 < K; k0 += 64) {
#pragma unroll
        for (int i = 0; i < 2; ++i) {
            const int cid = i * 256 + tid;
            const int row = cid >> 3, kc = cid & 7;
            const int slot = kc ^ (row & 7);
            const float* sa = A + (size_t)(bm + row) * K + k0 + kc * 8;
            f32x4 v0 = *(const f32x4*)sa;
            f32x4 v1 = *(const f32x4*)(sa + 4);
            bf16x8 ab;
#pragma unroll
            for (int j = 0; j < 4; ++j) { ab[j] = (__bf16)v0[j]; ab[4 + j] = (__bf16)v1[j]; }
            *(bf16x8*)&sA[row * 64 + slot * 8] = ab;
            *(bf16x8*)&sW[row * 64 + slot * 8] =
                *(const bf16x8*)(W + (size_t)(bn + row) * K + k0 + kc * 8);
        }
        __syncthreads();
#pragma unroll
        for (int ks = 0; ks < 2; ++ks) {
            const int kc = ks * 4 + fq;
            const int r0 = m_off + fr, r1 = m_off + 16 + fr;
            const int c0 = n_off + fr, c1 = n_off + 16 + fr;
            bf16x8 a0 = *(const bf16x8*)&sA[r0 * 64 + (kc ^ (r0 & 7)) * 8];
            bf16x8 a1 = *(const bf16x8*)&sA[r1 * 64 + (kc ^ (r1 & 7)) * 8];
            bf16x8 b0 = *(const bf16x8*)&sW[c0 * 64 + (kc ^ (c0 & 7)) * 8];
            bf16x8 b1 = *(const bf16x8*)&sW[c1 * 64 + (kc ^ (c1 & 7)) * 8];
            acc[0][0] = __builtin_amdgcn_mfma_f32_16x16x32_bf16(a0, b0, acc[0][0], 0, 0, 0);
            acc[0][1] = __builtin_amdgcn_mfma_f32_16x16x32_bf16(a0, b1, acc[0][1], 0, 0, 0);
            acc[1][0] = __builtin_amdgcn_mfma_f32_16x16x32_bf16(a1, b0, acc[1][0], 0, 0, 0);
            acc[1][1] = __builtin_amdgcn_mfma_f32_16x16x32_bf16(a1, b1, acc[1][1], 0, 0, 0);
        }
        __syncthreads();
    }
#pragma unroll
    for (int i = 0; i < 2; ++i)
#pragma unroll
        for (int j = 0; j < 2; ++j)
#pragma unroll
            for (int r = 0; r < 4; ++r)
                C[(size_t)(bm + m_off + i * 16 + fq * 4 + r) * N
                  + bn + n_off + j * 16 + fr] = acc[i][j][r];
}

// ---- same GEMM, transposed store: dst[(b*N + col)*Lb + t] (+ optional resid) ----
__global__ __launch_bounds__(256)
void gemm_bf16_tr(const float* __restrict__ A, const __bf16* __restrict__ W,
                  float* __restrict__ dst, const float* __restrict__ resid,
                  int M, int N, int K, int Lb)
{
    __shared__ __bf16 sA[64 * 64];
    __shared__ __bf16 sW[64 * 64];
    const int tid = threadIdx.x;
    const int bm = blockIdx.y * 64, bn = blockIdx.x * 64;
    const int lane = tid & 63, wv = tid >> 6;
    const int m_off = (wv & 1) * 32, n_off = (wv >> 1) * 32;
    const int fr = lane & 15, fq = lane >> 4;
    f32x4 acc[2][2] = {};

    for (int k0 = 0; k0 < K; k0 += 64) {
#pragma unroll
        for (int i = 0; i < 2; ++i) {
            const int cid = i * 256 + tid;
            const int row = cid >> 3, kc = cid & 7;
            const int slot = kc ^ (row & 7);
            const float* sa = A + (size_t)(bm + row) * K + k0 + kc * 8;
            f32x4 v0 = *(const f32x4*)sa;
            f32x4 v1 = *(const f32x4*)(sa + 4);
            bf16x8 ab;
#pragma unroll
            for (int j = 0; j < 4; ++j) { ab[j] = (__bf16)v0[j]; ab[4 + j] = (__bf16)v1[j]; }
            *(bf16x8*)&sA[row * 64 + slot * 8] = ab;
            *(bf16x8*)&sW[row * 64 + slot * 8] =
                *(const bf16x8*)(W + (size_t)(bn + row) * K + k0 + kc * 8);
        }
        __syncthreads();
#pragma unroll
        for (int ks = 0; ks < 2; ++ks) {
            const int kc = ks * 4 + fq;
            const int r0 = m_off + fr, r1 = m_off + 16 + fr;
            const int c0 = n_off + fr, c1 = n_off + 16 + fr;
            bf16x8 a0 = *(const bf16x8*)&sA[r0 * 64 + (kc ^ (r0 & 7)) * 8];
            bf16x8 a1 = *(const bf16x8*)&sA[r1 * 64 + (kc ^ (r1 & 7)) * 8];
            bf16x8 b0 = *(const bf16x8*)&sW[c0 * 64 + (kc ^ (c0 & 7)) * 8];
            bf16x8 b1 = *(const bf16x8*)&sW[c1 * 64 + (kc ^ (c1 & 7)) * 8];
            acc[0][0] = __builtin_amdgcn_mfma_f32_16x16x32_bf16(a0, b0, acc[0][0], 0, 0, 0);
            acc[0][1] = __builtin_amdgcn_mfma_f32_16x16x32_bf16(a0, b1, acc[0][1], 0, 0, 0);
            acc[1][0] = __builtin_amdgcn_mfma_f32_16x16x32_bf16(a1, b0, acc[1][0], 0, 0, 0);
            acc[1][1] = __builtin_amdgcn_mfma_f32_16x16x32_bf16(a1, b1, acc[1][1], 0, 0, 0);
        }
        __syncthreads();
    }
#pragma unroll
    for (int i = 0; i < 2; ++i)
#pragma unroll
        for (int j = 0; j < 2; ++j) {
            const int gn = bn + n_off + j * 16 + fr;
#pragma unroll
            for (int r = 0; r < 4; ++r) {
                const int gm = bm + m_off + i * 16 + fq * 4 + r;
                const int b = gm / Lb, t = gm - b * Lb;
                const size_t o = ((size_t)(b * N + gn)) * Lb + t;
                dst[o] = acc[i][j][r] + (resid ? resid[o] : 0.f);
            }
        }
}

// ------- fused conv+SiLU + split-K x_proj partial GEMM: pbuf[ks][M][64] -------
// grid (KS, M/64). A is computed on the fly from xz (conv over seq dim) and
// written to xi f32 (each (m,d) staged exactly once across the grid).
__global__ __launch_bounds__(256)
void fused_xp(const float* __restrict__ xz, const float* __restrict__ conv_w,
              const float* __restrict__ conv_b, const __bf16* __restrict__ W,
              float* __restrict__ xi_out, float* __restrict__ pbuf,
              int M, int K, int KC, int Lb)
{
    __shared__ __bf16 sA[64 * 64];
    __shared__ __bf16 sW[64 * 64];
    const int tid = threadIdx.x;
    const int bm = blockIdx.y * 64;
    const int kb = blockIdx.x * KC;
    const int lane = tid & 63, wv = tid >> 6;
    const int m_off = (wv & 1) * 32, n_off = (wv >> 1) * 32;
    const int fr = lane & 15, fq = lane >> 4;
    const int DI = K;
    const int b = bm / Lb;          // stripe lies in one sequence (Lb % 64 == 0)
    const int tbase = bm - b * Lb;
    f32x4 acc[2][2] = {};

    for (int k0 = kb; k0 < kb + KC; k0 += 64) {
#pragma unroll
        for (int i = 0; i < 2; ++i) {
            const int cid = i * 256 + tid;
            const int row = cid >> 3, kc = cid & 7;
            const int slot = kc ^ (row & 7);
            const int d0 = k0 + kc * 8;
            const int t = tbase + row;
            // conv + silu for 8 channels
            f32x4 a0 = *(const f32x4*)&conv_b[d0];
            f32x4 a1 = *(const f32x4*)&conv_b[d0 + 4];
            f32x4 wc[8];
#pragma unroll
            for (int cch = 0; cch < 8; ++cch)
                wc[cch] = *(const f32x4*)&conv_w[(size_t)(d0 + cch) * 4];
#pragma unroll
            for (int j = 0; j < 4; ++j) {
                const int tt = t - 3 + j;
                if (tt >= 0) {
                    const float* src = xz + (size_t)(b * Lb + tt) * (2 * DI) + d0;
                    f32x4 v0 = *(const f32x4*)src;
                    f32x4 v1 = *(const f32x4*)(src + 4);
#pragma unroll
                    for (int cch = 0; cch < 4; ++cch) {
                        a0[cch] = fmaf(wc[cch][j], v0[cch], a0[cch]);
                        a1[cch] = fmaf(wc[4 + cch][j], v1[cch], a1[cch]);
                    }
                }
            }
            f32x4 r0, r1; bf16x8 ab;
#pragma unroll
            for (int cch = 0; cch < 4; ++cch) {
                const float u0 = a0[cch], u1 = a1[cch];
                const float s0 = u0 / (1.f + __expf(-u0));
                const float s1 = u1 / (1.f + __expf(-u1));
                r0[cch] = s0; r1[cch] = s1;
                ab[cch] = (__bf16)s0; ab[4 + cch] = (__bf16)s1;
            }
            const size_t mrow = (size_t)(bm + row);
            *(f32x4*)&xi_out[mrow * DI + d0] = r0;
            *(f32x4*)&xi_out[mrow * DI + d0 + 4] = r1;
            *(bf16x8*)&sA[row * 64 + slot * 8] = ab;
            *(bf16x8*)&sW[row * 64 + slot * 8] =
                *(const bf16x8*)(W + (size_t)row * K + k0 + kc * 8);
        }
        __syncthreads();
#pragma unroll
        for (int ks = 0; ks < 2; ++ks) {
            const int kc = ks * 4 + fq;
            const int r0 = m_off + fr, r1 = m_off + 16 + fr;
            const int c0 = n_off + fr, c1 = n_off + 16 + fr;
            bf16x8 a0 = *(const bf16x8*)&sA[r0 * 64 + (kc ^ (r0 & 7)) * 8];
            bf16x8 a1 = *(const bf16x8*)&sA[r1 * 64 + (kc ^ (r1 & 7)) * 8];
            bf16x8 b0 = *(const bf16x8*)&sW[c0 * 64 + (kc ^ (c0 & 7)) * 8];
            bf16x8 b1 = *(const bf16x8*)&sW[c1 * 64 + (kc ^ (c1 & 7)) * 8];
            acc[0][0] = __builtin_amdgcn_mfma_f32_16x16x32_bf16(a0, b0, acc[0][0], 0, 0, 0);
            acc[0][1] = __builtin_amdgcn_mfma_f32_16x16x32_bf16(a0, b1, acc[0][1], 0, 0, 0);
            acc[1][0] = __builtin_amdgcn_mfma_f32_16x16x32_bf16(a1, b0, acc[1][0], 0, 0, 0);
            acc[1][1] = __builtin_amdgcn_mfma_f32_16x16x32_bf16(a1, b1, acc[1][1], 0, 0, 0);
        }
        __syncthreads();
    }
    float* out = pbuf + (size_t)blockIdx.x * M * 64;
#pragma unroll
    for (int i = 0; i < 2; ++i)
#pragma unroll
        for (int j = 0; j < 2; ++j)
#pragma unroll
            for (int r = 0; r < 4; ++r)
                out[(size_t)(bm + m_off + i * 16 + fq * 4 + r) * 64
                    + n_off + j * 16 + fr] = acc[i][j][r];
}

// ---------------- scan phase 1: per-chunk propagator + local end state ----------------
// Stages x_dbl chunk from split-K partials, computes dt in f32 in LDS.
// block = 256 (16 s x 16 d), grid = Bb * P * DI/16.
__global__ __launch_bounds__(256)
void scan_p1(const float* __restrict__ xi, const float* __restrict__ pbuf,
             const float* __restrict__ dtw, const float* __restrict__ dtb,
             const float* __restrict__ A_log,
             float* __restrict__ wsA, float* __restrict__ wsB,
             int Bb, int Lb, int DI, int R, int P, int KS)
{
    __shared__ float s_xd[SCAN_TC][64];
    __shared__ float s_dt[SCAN_TC][16];
    __shared__ float s_xi[SCAN_TC][16];
    __shared__ float s_w[16 * 33];
    __shared__ float s_db[16];
    const int tid = threadIdx.x;
    const int s = tid & 15, dl = tid >> 4;
    const int nDB = DI / 16;
    const int cpb = P * nDB;
    const int b = blockIdx.x / cpb;
    const int rem = blockIdx.x % cpb;
    const int c = rem / nDB;
    const int d0 = (rem % nDB) * 16;
    const int d = d0 + dl;
    const int M = Bb * Lb;
    const size_t rowbase = (size_t)b * Lb + (size_t)c * SCAN_TC;

    for (int idx = tid; idx < 16 * R; idx += 256)
        s_w[(idx / R) * 33 + (idx % R)] = dtw[(size_t)(d0 + idx / R) * R + idx % R];
    if (tid < 16) s_db[tid] = dtb[d0 + tid];
#pragma unroll
    for (int i = 0; i < 8; ++i) {
        const int e = i * 256 + tid;
        const int tt = e >> 6, col = e & 63;
        const size_t m = rowbase + tt;
        float v = 0.f;
        for (int ks = 0; ks < KS; ++ks)
            v += pbuf[(size_t)ks * M * 64 + m * 64 + col];
        s_xd[tt][col] = v;
    }
#pragma unroll
    for (int i = 0; i < 2; ++i) {
        const int e = i * 256 + tid;
        const int tt = e >> 4, dd = e & 15;
        s_xi[tt][dd] = xi[(rowbase + tt) * DI + d0 + dd];
    }
    __syncthreads();
#pragma unroll
    for (int i = 0; i < 2; ++i) {
        const int pr = i * 256 + tid;
        const int tt = pr >> 4, dd = pr & 15;
        float v = s_db[dd];
        for (int r = 0; r < R; ++r) v = fmaf(s_xd[tt][r], s_w[dd * 33 + r], v);
        s_dt[tt][dd] = fmaxf(v, 0.f) + log1pf(__expf(-fabsf(v)));
    }
    __syncthreads();
    const float A = -__expf(A_log[(size_t)d * 16 + s]);
    float h = 0.f, sdt = 0.f;
#pragma unroll 4
    for (int t = 0; t < SCAN_TC; ++t) {
        const float dtv = s_dt[t][dl];
        const float xv  = s_xi[t][dl];
        const float Bv  = s_xd[t][R + s];
        h = fmaf(__expf(dtv * A), h, dtv * Bv * xv);
        sdt += dtv;
    }
    const size_t o = ((size_t)(b * P + c) * DI + d) * 16 + s;
    wsA[o] = __expf(sdt * A);
    wsB[o] = h;
}

// ---------------- scan phases 2+3: rebuild h0, re-scan chunk, emit y ----------------
__global__ __launch_bounds__(256)
void scan_p23(const float* __restrict__ xi, const float* __restrict__ pbuf,
              const float* __restrict__ xz,
              const float* __restrict__ dtw, const float* __restrict__ dtb,
              const float* __restrict__ A_log, const float* __restrict__ Dp,
              const float* __restrict__ wsA, const float* __restrict__ wsB,
              float* __restrict__ y,
              int Bb, int Lb, int DI, int R, int P, int KS)
{
    __shared__ float s_xd[SCAN_TC][64];
    __shared__ float s_dt[SCAN_TC][16];
    __shared__ float s_xi[SCAN_TC][16];
    __shared__ float s_z [SCAN_TC][16];
    __shared__ float s_w[16 * 33];
    __shared__ float s_db[16];
    const int tid = threadIdx.x;
    const int s = tid & 15, dl = tid >> 4;
    const int nDB = DI / 16;
    const int cpb = P * nDB;
    const int b = blockIdx.x / cpb;
    const int rem = blockIdx.x % cpb;
    const int c = rem / nDB;
    const int d0 = (rem % nDB) * 16;
    const int d = d0 + dl;
    const int M = Bb * Lb;
    const size_t rowbase = (size_t)b * Lb + (size_t)c * SCAN_TC;

    for (int idx = tid; idx < 16 * R; idx += 256)
        s_w[(idx / R) * 33 + (idx % R)] = dtw[(size_t)(d0 + idx / R) * R + idx % R];
    if (tid < 16) s_db[tid] = dtb[d0 + tid];
#pragma unroll
    for (int i = 0; i < 8; ++i) {
        const int e = i * 256 + tid;
        const int tt = e >> 6, col = e & 63;
        const size_t m = rowbase + tt;
        float v = 0.f;
        for (int ks = 0; ks < KS; ++ks)
            v += pbuf[(size_t)ks * M * 64 + m * 64 + col];
        s_xd[tt][col] = v;
    }
#pragma unroll
    for (int i = 0; i < 2; ++i) {
        const int e = i * 256 + tid;
        const int tt = e >> 4, dd = e & 15;
        s_xi[tt][dd] = xi[(rowbase + tt) * DI + d0 + dd];
        s_z [tt][dd] = xz[(rowbase + tt) * (size_t)(2 * DI) + DI + d0 + dd];
    }
    __syncthreads();
#pragma unroll
    for (int i = 0; i < 2; ++i) {
        const int pr = i * 256 + tid;
        const int tt = pr >> 4, dd = pr & 15;
        float v = s_db[dd];
        for (int r = 0; r < R; ++r) v = fmaf(s_xd[tt][r], s_w[dd * 33 + r], v);
        s_dt[tt][dd] = fmaxf(v, 0.f) + log1pf(__expf(-fabsf(v)));
    }
    __syncthreads();
    const float A = -__expf(A_log[(size_t)d * 16 + s]);
    const float Dv = Dp[d];

    float h = 0.f;
    for (int cc = 0; cc < c; ++cc) {
        const size_t oc = ((size_t)(b * P + cc) * DI + d) * 16 + s;
        h = fmaf(wsA[oc], h, wsB[oc]);
    }
#pragma unroll 2
    for (int t = 0; t < SCAN_TC; ++t) {
        const float dtv = s_dt[t][dl];
        const float xv  = s_xi[t][dl];
        const float Bv  = s_xd[t][R + s];
        const float Cv  = s_xd[t][R + 16 + s];
        h = fmaf(__expf(dtv * A), h, dtv * Bv * xv);
        float p = h * Cv;
        p += __shfl_xor(p, 1, 16);
        p += __shfl_xor(p, 2, 16);
        p += __shfl_xor(p, 4, 16);
        p += __shfl_xor(p, 8, 16);
        if (s == 0) {
            const float zv = s_z[t][dl];
            const float sig = __fdividef(zv, 1.f + __expf(-zv));
            y[(rowbase + t) * DI + d] = (p + Dv * xv) * sig;
        }
    }
}

extern "C" void kernel_launch(void* const* d_in, const int* in_sizes, int n_in,
                              void* d_out, int out_size, void* d_ws, size_t ws_size,
                              hipStream_t stream)
{
    const float* x       = (const float*)d_in[0];
    const float* a_in_w  = (const float*)d_in[1];
    const float* a_convw = (const float*)d_in[2];
    const float* a_convb = (const float*)d_in[3];
    const float* a_xproj = (const float*)d_in[4];
    const float* a_dtw   = (const float*)d_in[5];
    const float* a_dtb   = (const float*)d_in[6];
    const float* a_Alog  = (const float*)d_in[7];
    const float* a_Dp    = (const float*)d_in[8];
    const float* a_outw  = (const float*)d_in[9];
    const float* b_in_w  = (const float*)d_in[10];
    const float* b_convw = (const float*)d_in[11];
    const float* b_convb = (const float*)d_in[12];
    const float* b_xproj = (const float*)d_in[13];
    const float* b_dtw   = (const float*)d_in[14];
    const float* b_dtb   = (const float*)d_in[15];
    const float* b_Alog  = (const float*)d_in[16];
    const float* b_Dp    = (const float*)d_in[17];
    const float* b_outw  = (const float*)d_in[18];

    float* ws = (float*)d_ws;
    float* buf_x   = ws;                 // 262144
    float* buf_xz  = buf_x  + 262144;    // 1048576
    float* buf_xi  = buf_xz + 1048576;   // 524288
    float* buf_y   = buf_xi + 524288;    // 524288
    float* buf_x2  = buf_y  + 524288;    // 262144
    float* buf_wsA = buf_x2 + 262144;    // 262144
    float* buf_wsB = buf_wsA + 262144;   // 262144
    float* buf_pk  = buf_wsB + 262144;   // 262144 (KS x M x 64 partials)
    __bf16* wb      = (__bf16*)(buf_pk + 262144);
    __bf16* wb_a_in  = wb;                        // 2097152
    __bf16* wb_a_out = wb_a_in + 2097152;         // 1048576
    __bf16* wb_b_in  = wb_a_out + 1048576;        // 524288
    __bf16* wb_b_out = wb_b_in + 524288;          // 262144
    __bf16* wb_xp_a  = wb_b_out + 262144;         // 131072 (2,64,1024)
    __bf16* wb_xp_b  = wb_xp_a + 131072;          // 65536  (2,64,512) padded

    // weight conversions (every launch; deterministic)
    {
        const int n0 = 2097152, n1 = 1048576, n2 = 524288, n3 = 262144;
        const int nt = (n0 + n1 + n2 + n3) / 4;
        cvt4<<<(nt + 255) / 256, 256, 0, stream>>>(
            a_in_w, a_outw, b_in_w, b_outw,
            wb_a_in, wb_a_out, wb_b_in, wb_b_out, n0, n1, n2, n3);
        cvt_pad2<<<(131072 + 65536) / 256, 256, 0, stream>>>(
            a_xproj, b_xproj, wb_xp_a, wb_xp_b);
    }

    // -------- group a: Bb=2, Lb=256, dm=512, di=1024, R=32, P=8, KS=8 --------
    for (int k = 0; k < 2; ++k) {
        const int Bb = 2, Lb = 256, DM = 512, DI = 1024, R = 32, P = 8, KS = 8;
        const int M = Bb * Lb;
        const float* src = (k == 0) ? x : buf_x;
        gemm_bf16<<<dim3(2 * DI / 64, M / 64), 256, 0, stream>>>(
            src, wb_a_in + (size_t)k * 2 * DI * DM, buf_xz, M, 2 * DI, DM);
        fused_xp<<<dim3(KS, M / 64), 256, 0, stream>>>(
            buf_xz, a_convw + (size_t)k * DI * 4, a_convb + (size_t)k * DI,
            wb_xp_a + (size_t)k * 64 * DI, buf_xi, buf_pk, M, DI, DI / KS, Lb);
        scan_p1<<<Bb * P * DI / 16, 256, 0, stream>>>(
            buf_xi, buf_pk, a_dtw + (size_t)k * DI * R, a_dtb + (size_t)k * DI,
            a_Alog + (size_t)k * DI * 16, buf_wsA, buf_wsB, Bb, Lb, DI, R, P, KS);
        scan_p23<<<Bb * P * DI / 16, 256, 0, stream>>>(
            buf_xi, buf_pk, buf_xz, a_dtw + (size_t)k * DI * R, a_dtb + (size_t)k * DI,
            a_Alog + (size_t)k * DI * 16, a_Dp + (size_t)k * DI,
            buf_wsA, buf_wsB, buf_y, Bb, Lb, DI, R, P, KS);
        if (k == 0)
            gemm_bf16<<<dim3(DM / 64, M / 64), 256, 0, stream>>>(
                buf_y, wb_a_out + (size_t)k * DM * DI, buf_x, M, DM, DI);
        else
            gemm_bf16_tr<<<dim3(DM / 64, M / 64), 256, 0, stream>>>(
                buf_y, wb_a_out + (size_t)k * DM * DI, buf_x2, nullptr, M, DM, DI, Lb);
    }

    // -------- group b: Bb=2, Lb=512, dm=256, di=512, R=16, P=16, KS=4 --------
    for (int k = 0; k < 2; ++k) {
        const int Bb = 2, Lb = 512, DM = 256, DI = 512, R = 16, P = 16, KS = 4;
        const int M = Bb * Lb;
        const float* src = (k == 0) ? buf_x2 : buf_x;
        gemm_bf16<<<dim3(2 * DI / 64, M / 64), 256, 0, stream>>>(
            src, wb_b_in + (size_t)k * 2 * DI * DM, buf_xz, M, 2 * DI, DM);
        fused_xp<<<dim3(KS, M / 64), 256, 0, stream>>>(
            buf_xz, b_convw + (size_t)k * DI * 4, b_convb + (size_t)k * DI,
            wb_xp_b + (size_t)k * 64 * DI, buf_xi, buf_pk, M, DI, DI / KS, Lb);
        scan_p1<<<Bb * P * DI / 16, 256, 0, stream>>>(
            buf_xi, buf_pk, b_dtw + (size_t)k * DI * R, b_dtb + (size_t)k * DI,
            b_Alog + (size_t)k * DI * 16, buf_wsA, buf_wsB, Bb, Lb, DI, R, P, KS);
        scan_p23<<<Bb * P * DI / 16, 256, 0, stream>>>(
            buf_xi, buf_pk, buf_xz, b_dtw + (size_t)k * DI * R, b_dtb + (size_t)k * DI,
            b_Alog + (size_t)k * DI * 16, b_Dp + (size_t)k * DI,
            buf_wsA, buf_wsB, buf_y, Bb, Lb, DI, R, P, KS);
        if (k == 0)
            gemm_bf16<<<dim3(DM / 64, M / 64), 256, 0, stream>>>(
                buf_y, wb_b_out + (size_t)k * DM * DI, buf_x, M, DM, DI);
        else
            gemm_bf16_tr<<<dim3(DM / 64, M / 64), 256, 0, stream>>>(
                buf_y, wb_b_out + (size_t)k * DM * DI, (float*)d_out, x, M, DM, DI, Lb);
    }
}